// Round 2
// baseline (120.359 us; speedup 1.0000x reference)
//
#include <hip/hip_runtime.h>

// Problem constants (from reference): B=4, N=256, FE=8, CIN=16, COUT=16, H=64
#define B_    4
#define N_    256
#define FE_   8
#define CIN_  16
#define COUT_ 16
#define H_    64
#define S_    32   // i-slices: each K1 block handles N_/S_ = 8 rows of i

// Math:
// out[b,j,d] = sum_c node[b,j,c] * ( Wsum[b,j,c,d] + root[c,d] )
// Wsum[b,j]  = Hsum[b,j,:] @ W2 + N*b2
// Hsum[b,j,h]= sum_i relu( edge[b,i,j,:] @ W1 + b1 )[h]
//
// K1: partial[s][b][jt][jj][h] = sum over 8 i-rows; lane = jj (coalesced e loads,
//     W1/b1 via wave-uniform scalar loads). K2: reduce over s + steps 2-3.

__global__ __launch_bounds__(256) void k1_partial_hsum(
    const float* __restrict__ edge_adj,   // [B,N,N,FE]
    const float* __restrict__ W1,         // [FE,H]
    const float* __restrict__ b1,         // [H]
    float* __restrict__ partial)          // [S_*B_*4][64][64]
{
    const int blk = blockIdx.x;           // s*16 + b*4 + jt
    const int s   = blk >> 4;
    const int b   = (blk >> 2) & 3;
    const int jt  = blk & 3;
    const int t    = threadIdx.x;
    const int lane = t & 63;              // jj
    const int w    = t >> 6;              // wave 0..3

    __shared__ float Hs[H_][65];          // [h][jj], +1 pad -> conflict-free

    // zero the LDS accumulator
    for (int idx = t; idx < H_ * 65; idx += 256) ((float*)Hs)[idx] = 0.f;

    // each wave owns 2 i-rows; e-rows -> 16 VGPRs, fully coalesced loads
    const int i0 = s * 8 + w * 2;
    const int j  = jt * 64 + lane;
    const float* e0p = edge_adj + (((size_t)b * N_ + i0)     * N_ + j) * FE_;
    const float* e1p = edge_adj + (((size_t)b * N_ + i0 + 1) * N_ + j) * FE_;
    const float4 e0a = ((const float4*)e0p)[0];
    const float4 e0b = ((const float4*)e0p)[1];
    const float4 e1a = ((const float4*)e1p)[0];
    const float4 e1b = ((const float4*)e1p)[1];

    __syncthreads();

    #pragma unroll 4
    for (int h = 0; h < H_; ++h) {
        // wave-uniform indices -> compiler emits s_load (K$-resident, 2 KB total)
        const float w0 = W1[0 * H_ + h];
        const float w1 = W1[1 * H_ + h];
        const float w2 = W1[2 * H_ + h];
        const float w3 = W1[3 * H_ + h];
        const float w4 = W1[4 * H_ + h];
        const float w5 = W1[5 * H_ + h];
        const float w6 = W1[6 * H_ + h];
        const float w7 = W1[7 * H_ + h];
        const float bb = b1[h];

        float v0 = bb, v1 = bb;
        v0 = fmaf(e0a.x, w0, v0);  v1 = fmaf(e1a.x, w0, v1);
        v0 = fmaf(e0a.y, w1, v0);  v1 = fmaf(e1a.y, w1, v1);
        v0 = fmaf(e0a.z, w2, v0);  v1 = fmaf(e1a.z, w2, v1);
        v0 = fmaf(e0a.w, w3, v0);  v1 = fmaf(e1a.w, w3, v1);
        v0 = fmaf(e0b.x, w4, v0);  v1 = fmaf(e1b.x, w4, v1);
        v0 = fmaf(e0b.y, w5, v0);  v1 = fmaf(e1b.y, w5, v1);
        v0 = fmaf(e0b.z, w6, v0);  v1 = fmaf(e1b.z, w6, v1);
        v0 = fmaf(e0b.w, w7, v0);  v1 = fmaf(e1b.w, w7, v1);

        const float r = fmaxf(v0, 0.f) + fmaxf(v1, 0.f);
        // banks: (h*65 + lane) % 32 == (h + lane) % 32 -> 2-way max (free)
        atomicAdd(&Hs[h][lane], r);
    }
    __syncthreads();

    // write [jj][h] contiguous, coalesced b32 stores
    float* dst = partial + (size_t)blk * (64 * 64);
    #pragma unroll 4
    for (int k = 0; k < 16; ++k) {
        const int cell = k * 256 + t;       // cell = jj*64 + h
        dst[cell] = Hs[cell & 63][cell >> 6];
    }
}

__global__ __launch_bounds__(256) void k2_output(
    const float* __restrict__ node_attr,  // [B,N,CIN]
    const float* __restrict__ W2,         // [H, CIN*COUT]
    const float* __restrict__ b2,         // [CIN*COUT]
    const float* __restrict__ root,       // [CIN,COUT]
    const float* __restrict__ partial,    // [S_*B_*4][64][64]
    float* __restrict__ out)              // [B,N,COUT]
{
    const int bj = blockIdx.x;            // b*N + j
    const int b  = bj >> 8;
    const int j  = bj & (N_ - 1);
    const int jt = j >> 6;
    const int jj = j & 63;
    const int t  = threadIdx.x;

    __shared__ float sp[4][H_];
    __shared__ float Hsum[H_];
    __shared__ float contrib[CIN_][COUT_];

    // reduce the S_ partials for this (b,j); coalesced 256B reads per wave
    {
        const int sw = t >> 6;            // 0..3
        const int h  = t & 63;
        float a = 0.f;
        #pragma unroll
        for (int k = 0; k < 8; ++k) {
            const int s = sw + k * 4;
            a += partial[(((size_t)(s * 16 + b * 4 + jt)) * 64 + jj) * 64 + h];
        }
        sp[sw][h] = a;
    }
    __syncthreads();
    if (t < H_) Hsum[t] = sp[0][t] + sp[1][t] + sp[2][t] + sp[3][t];
    __syncthreads();

    // step 2: Wsum[t], t = c*COUT + d; W2 coalesced (L2-hot, 64 KB)
    float ws = (float)N_ * b2[t];
    #pragma unroll 8
    for (int h = 0; h < H_; ++h) {
        ws = fmaf(Hsum[h], W2[h * (CIN_ * COUT_) + t], ws);
    }

    // step 3: out[d] = sum_c node[c] * (Wsum[c,d] + root[c,d])
    const int c = t >> 4;
    const int d = t & 15;
    const float nodec = node_attr[((size_t)b * N_ + j) * CIN_ + c];
    contrib[c][d] = nodec * (ws + root[t]);
    __syncthreads();

    if (t < COUT_) {
        float o = 0.f;
        #pragma unroll
        for (int cc = 0; cc < CIN_; ++cc) o += contrib[cc][t];
        out[((size_t)b * N_ + j) * COUT_ + t] = o;
    }
}

extern "C" void kernel_launch(void* const* d_in, const int* in_sizes, int n_in,
                              void* d_out, int out_size, void* d_ws, size_t ws_size,
                              hipStream_t stream) {
    const float* node_attr = (const float*)d_in[0];  // [B,N,CIN]
    const float* edge_adj  = (const float*)d_in[1];  // [B,N,N,FE]
    const float* W1        = (const float*)d_in[2];  // [FE,H]
    const float* b1        = (const float*)d_in[3];  // [H]
    const float* W2        = (const float*)d_in[4];  // [H,CIN*COUT]
    const float* b2        = (const float*)d_in[5];  // [CIN*COUT]
    const float* root      = (const float*)d_in[6];  // [CIN,COUT]
    float* out = (float*)d_out;                      // [B,N,COUT]

    float* partial = (float*)d_ws;                   // 512 * 4096 * 4B = 8 MB

    k1_partial_hsum<<<dim3(S_ * B_ * 4), dim3(256), 0, stream>>>(
        edge_adj, W1, b1, partial);
    k2_output<<<dim3(B_ * N_), dim3(256), 0, stream>>>(
        node_attr, W2, b2, root, partial, out);
}

// Round 3
// 85.440 us; speedup vs baseline: 1.4087x; 1.4087x over previous
//
#include <hip/hip_runtime.h>

// Problem constants (from reference): B=4, N=256, FE=8, CIN=16, COUT=16, H=64
#define B_    4
#define N_    256
#define FE_   8
#define CIN_  16
#define COUT_ 16
#define H_    64
#define S_    32   // i-slices: each K1 block handles N_/S_ = 8 rows of i

// Math:
// out[b,j,d] = sum_c node[b,j,c] * ( Wsum[b,j,c,d] + root[c,d] )
// Wsum[b,j]  = Hsum[b,j,:] @ W2 + N*b2
// Hsum[b,j,h]= sum_i relu( edge[b,i,j,:] @ W1 + b1 )[h]
//
// K1: lane = jj (coalesced edge loads, W1/b1 wave-uniform -> s_load).
//     Each thread keeps all 64 h-accumulators in VGPRs; cross-wave reduce is
//     two barriered LDS phases (NO atomics - R2's LDS float atomicAdd compiled
//     to a CAS loop and serialized the whole kernel at 47 us / 8.8% VALUBusy).
// K2: reduce the S_ partials + steps 2-3.

__global__ __launch_bounds__(256) void k1_partial_hsum(
    const float* __restrict__ edge_adj,   // [B,N,N,FE]
    const float* __restrict__ W1,         // [FE,H]
    const float* __restrict__ b1,         // [H]
    float* __restrict__ partial)          // [S_*B_*4][64*64]  (jj-major, h minor)
{
    const int blk = blockIdx.x;           // s*16 + b*4 + jt
    const int s   = blk >> 4;
    const int b   = (blk >> 2) & 3;
    const int jt  = blk & 3;
    const int t    = threadIdx.x;
    const int lane = t & 63;              // jj
    const int w    = t >> 6;              // wave 0..3

    __shared__ float bufA[64][H_ + 1];    // [jj][h], +1 pad -> 2-way banks (free)
    __shared__ float bufB[64][H_ + 1];

    // ---- load this wave's 2 e-rows (fully coalesced: 2 KB/row per wave) ----
    const int i0 = s * 8 + w * 2;
    const int j  = jt * 64 + lane;
    const float* e0p = edge_adj + (((size_t)b * N_ + i0)     * N_ + j) * FE_;
    const float* e1p = edge_adj + (((size_t)b * N_ + i0 + 1) * N_ + j) * FE_;
    const float4 e0a = ((const float4*)e0p)[0];
    const float4 e0b = ((const float4*)e0p)[1];
    const float4 e1a = ((const float4*)e1p)[0];
    const float4 e1b = ((const float4*)e1p)[1];

    // ---- all 64 h-accumulators in registers; W1/b1 uniform -> scalar loads ----
    float acc[H_];
    #pragma unroll
    for (int h = 0; h < H_; ++h) {
        const float w0 = W1[0 * H_ + h];
        const float w1 = W1[1 * H_ + h];
        const float w2 = W1[2 * H_ + h];
        const float w3 = W1[3 * H_ + h];
        const float w4 = W1[4 * H_ + h];
        const float w5 = W1[5 * H_ + h];
        const float w6 = W1[6 * H_ + h];
        const float w7 = W1[7 * H_ + h];
        const float bb = b1[h];

        float v0 = bb, v1 = bb;
        v0 = fmaf(e0a.x, w0, v0);  v1 = fmaf(e1a.x, w0, v1);
        v0 = fmaf(e0a.y, w1, v0);  v1 = fmaf(e1a.y, w1, v1);
        v0 = fmaf(e0a.z, w2, v0);  v1 = fmaf(e1a.z, w2, v1);
        v0 = fmaf(e0a.w, w3, v0);  v1 = fmaf(e1a.w, w3, v1);
        v0 = fmaf(e0b.x, w4, v0);  v1 = fmaf(e1b.x, w4, v1);
        v0 = fmaf(e0b.y, w5, v0);  v1 = fmaf(e1b.y, w5, v1);
        v0 = fmaf(e0b.z, w6, v0);  v1 = fmaf(e1b.z, w6, v1);
        v0 = fmaf(e0b.w, w7, v0);  v1 = fmaf(e1b.w, w7, v1);

        acc[h] = fmaxf(v0, 0.f) + fmaxf(v1, 0.f);
    }

    // ---- cross-wave reduce, no atomics: w0->A, w2->B write; w1->A, w3->B add
    float (*mybuf)[H_ + 1] = (w < 2) ? bufA : bufB;
    if ((w & 1) == 0) {
        #pragma unroll
        for (int h = 0; h < H_; ++h) mybuf[lane][h] = acc[h];
    }
    __syncthreads();
    if ((w & 1) == 1) {
        #pragma unroll
        for (int h = 0; h < H_; ++h) mybuf[lane][h] += acc[h];
    }
    __syncthreads();

    // ---- fused final add + coalesced store: partial[blk][jj*64+h] ----
    float* dst = partial + (size_t)blk * (64 * H_);
    #pragma unroll
    for (int k = 0; k < 16; ++k) {
        const int cell = k * 256 + t;          // = jj*64 + h; per wave: jj fixed, h=lane
        const int jj   = cell >> 6;
        const int h    = cell & 63;
        dst[cell] = bufA[jj][h] + bufB[jj][h];
    }
}

__global__ __launch_bounds__(256) void k2_output(
    const float* __restrict__ node_attr,  // [B,N,CIN]
    const float* __restrict__ W2,         // [H, CIN*COUT]
    const float* __restrict__ b2,         // [CIN*COUT]
    const float* __restrict__ root,       // [CIN,COUT]
    const float* __restrict__ partial,    // [S_*B_*4][64*64]
    float* __restrict__ out)              // [B,N,COUT]
{
    const int bj = blockIdx.x;            // b*N + j
    const int b  = bj >> 8;
    const int j  = bj & (N_ - 1);
    const int jt = j >> 6;
    const int jj = j & 63;
    const int t  = threadIdx.x;

    __shared__ float sp[4][H_];
    __shared__ float Hsum[H_];
    __shared__ float contrib[CIN_][COUT_];

    // reduce the S_ partials for this (b,j); 256B coalesced reads per wave
    {
        const int sw = t >> 6;            // 0..3
        const int h  = t & 63;
        float a = 0.f;
        #pragma unroll
        for (int k = 0; k < 8; ++k) {
            const int s = sw + k * 4;
            a += partial[(((size_t)(s * 16 + b * 4 + jt)) * 64 + jj) * 64 + h];
        }
        sp[sw][h] = a;
    }
    __syncthreads();
    if (t < H_) Hsum[t] = sp[0][t] + sp[1][t] + sp[2][t] + sp[3][t];
    __syncthreads();

    // step 2: Wsum[t], t = c*COUT + d; W2 coalesced (L2-hot, 64 KB)
    float ws = (float)N_ * b2[t];
    #pragma unroll 8
    for (int h = 0; h < H_; ++h) {
        ws = fmaf(Hsum[h], W2[h * (CIN_ * COUT_) + t], ws);
    }

    // step 3: out[d] = sum_c node[c] * (Wsum[c,d] + root[c,d])
    const int c = t >> 4;
    const int d = t & 15;
    const float nodec = node_attr[((size_t)b * N_ + j) * CIN_ + c];
    contrib[c][d] = nodec * (ws + root[t]);
    __syncthreads();

    if (t < COUT_) {
        float o = 0.f;
        #pragma unroll
        for (int cc = 0; cc < CIN_; ++cc) o += contrib[cc][t];
        out[((size_t)b * N_ + j) * COUT_ + t] = o;
    }
}

extern "C" void kernel_launch(void* const* d_in, const int* in_sizes, int n_in,
                              void* d_out, int out_size, void* d_ws, size_t ws_size,
                              hipStream_t stream) {
    const float* node_attr = (const float*)d_in[0];  // [B,N,CIN]
    const float* edge_adj  = (const float*)d_in[1];  // [B,N,N,FE]
    const float* W1        = (const float*)d_in[2];  // [FE,H]
    const float* b1        = (const float*)d_in[3];  // [H]
    const float* W2        = (const float*)d_in[4];  // [H,CIN*COUT]
    const float* b2        = (const float*)d_in[5];  // [CIN*COUT]
    const float* root      = (const float*)d_in[6];  // [CIN,COUT]
    float* out = (float*)d_out;                      // [B,N,COUT]

    float* partial = (float*)d_ws;                   // 512 * 4096 * 4B = 8 MB

    k1_partial_hsum<<<dim3(S_ * B_ * 4), dim3(256), 0, stream>>>(
        edge_adj, W1, b1, partial);
    k2_output<<<dim3(B_ * N_), dim3(256), 0, stream>>>(
        node_attr, W2, b2, root, partial, out);
}